// Round 16
// baseline (153.512 us; speedup 1.0000x reference)
//
#include <hip/hip_runtime.h>

#define HW    16384   // 128*128
#define Wh    128
#define Cin   64
#define C2    32
#define HW4   4096    // 64*64

typedef short short8 __attribute__((ext_vector_type(8)));     // 8 bf16 = 4 VGPRs
typedef float float4v __attribute__((ext_vector_type(4)));
typedef unsigned uint4v __attribute__((ext_vector_type(4)));

#define LOG2E 1.44269504f
#define OFFE  43.2808512f   // 30*log2(e): exp(s-30) == exp2(s*log2e - OFFE)

__device__ __forceinline__ unsigned pack2bf16(float lo, float hi) {
  unsigned ul = __builtin_bit_cast(unsigned, lo);
  unsigned uh = __builtin_bit_cast(unsigned, hi);
  ul = (ul + 0x7fffu + ((ul >> 16) & 1u)) >> 16;
  uh = (uh + 0x7fffu + ((uh >> 16) & 1u)) & 0xffff0000u;
  return ul | uh;
}
__device__ __forceinline__ unsigned short f2bf(float f) {
  unsigned u = __builtin_bit_cast(unsigned, f);
  return (unsigned short)((u + 0x7fffu + ((u >> 16) & 1u)) >> 16);
}
// RTZ-truncate two fp32 to bf16, lo in [15:0], hi in [31:16]
__device__ __forceinline__ unsigned packtrunc(float lo, float hi) {
  return __builtin_amdgcn_perm(__builtin_bit_cast(unsigned, hi),
                               __builtin_bit_cast(unsigned, lo), 0x07060302u);
}

// ---------------------------------------------------------------------------
// Kernel 1: FUSED theta+phi+g conv (+2x2 maxpool) — R29 form (repack folded
// in bitwise-identically; tile-major V store). Unchanged this round.
// ---------------------------------------------------------------------------
__global__ __launch_bounds__(256) void conv_qkv_kern(
    const float* __restrict__ x,
    const float* __restrict__ wt, const float* __restrict__ bt,
    const float* __restrict__ wp, const float* __restrict__ bp,
    const float* __restrict__ wg, const float* __restrict__ bg,
    unsigned short* __restrict__ Q, unsigned short* __restrict__ K,
    unsigned short* __restrict__ Vt) {
  __shared__ float smX[2][8][256];               // 16 KB, double-buffered
  __shared__ unsigned short smV[8][64];          // 1 KB
  int tid = threadIdx.x;
  int og = blockIdx.y, bz = blockIdx.z;
  int pxbase = blockIdx.x * 2 * Wh;              // full-res rows 2i, 2i+1
  int jloc = tid >> 2;                           // pooled col 0..63
  int rpar = (tid >> 1) & 1, cpar = tid & 1;
  int myPx = rpar * Wh + 2 * jloc + cpar;        // local pixel 0..255
  const float* xb = x + (size_t)bz * Cin * HW + pxbase;
  const float* wts = wt + (size_t)og * 8 * Cin;  // uniform -> s_load
  const float* wps = wp + (size_t)og * 8 * Cin;
  const float* wgs = wg + (size_t)og * 8 * Cin;

  // stage chunk: 512 float4 = 256 threads x 2; ch = f>>6, p4 = f&63
  auto stage = [&](int cb8, int buf) {
#pragma unroll
    for (int u = 0; u < 2; ++u) {
      int f = u * 256 + tid;
      int ch = f >> 6, p4 = f & 63;
      *(float4*)&smX[buf][ch][p4 * 4] =
          *(const float4*)(xb + (size_t)(cb8 * 8 + ch) * HW + p4 * 4);
    }
  };

  // acc[0..7]=theta (pre-scaled by LOG2E), acc[8..15]=phi, acc[16..23]=g
  float acc[24];
#pragma unroll
  for (int k = 0; k < 8; ++k) {
    acc[k] = bt[og * 8 + k] * LOG2E;             // == repack's bAll value
    acc[8 + k] = bp[og * 8 + k];
    acc[16 + k] = bg[og * 8 + k];
  }

  stage(0, 0);
  __syncthreads();
  for (int cb8 = 0; cb8 < 8; ++cb8) {
    if (cb8 < 7) stage(cb8 + 1, (cb8 + 1) & 1);  // loads fly over compute
    float xv[8];
#pragma unroll
    for (int u = 0; u < 8; ++u) xv[u] = smX[cb8 & 1][u][myPx];
#pragma unroll
    for (int u = 0; u < 8; ++u) {
      int ch = cb8 * 8 + u;
#pragma unroll
      for (int k = 0; k < 8; ++k) {
        acc[k]      = fmaf(wts[k * Cin + ch] * LOG2E, xv[u], acc[k]);
        acc[8 + k]  = fmaf(wps[k * Cin + ch], xv[u], acc[8 + k]);
        acc[16 + k] = fmaf(wgs[k * Cin + ch], xv[u], acc[16 + k]);
      }
    }
    __syncthreads();                             // staged buf ready for next
  }

  int pp = blockIdx.x * 64 + jloc;               // global pooled pixel
  int p = pxbase + myPx;                         // global full-res pixel
  // theta -> Q
  {
    uint4 up;
    up.x = pack2bf16(acc[0], acc[1]); up.y = pack2bf16(acc[2], acc[3]);
    up.z = pack2bf16(acc[4], acc[5]); up.w = pack2bf16(acc[6], acc[7]);
    *(uint4*)(Q + ((size_t)bz * HW + p) * C2 + og * 8) = up;
  }
  // 2x2 maxpool across lane-mates {4j..4j+3}
  float aP[8], aG[8];
#pragma unroll
  for (int o = 0; o < 8; ++o) {
    float vp = acc[8 + o], vg = acc[16 + o];
    vp = fmaxf(vp, __shfl_xor(vp, 1)); vp = fmaxf(vp, __shfl_xor(vp, 2));
    vg = fmaxf(vg, __shfl_xor(vg, 1)); vg = fmaxf(vg, __shfl_xor(vg, 2));
    aP[o] = vp; aG[o] = vg;
  }
  if ((tid & 3) == 0) {
    int loc = pp & 31, tile = pp >> 5;
    int prow = ((loc & 4) << 2) + ((loc >> 3) << 2) + (loc & 3);   // S^T perm
    uint4 up;
    up.x = pack2bf16(aP[0], aP[1]); up.y = pack2bf16(aP[2], aP[3]);
    up.z = pack2bf16(aP[4], aP[5]); up.w = pack2bf16(aP[6], aP[7]);
    *(uint4*)(K + ((size_t)bz * HW4 + tile * 32 + prow) * C2 + og * 8) = up;
#pragma unroll
    for (int o = 0; o < 8; ++o) smV[o][tid >> 2] = f2bf(aG[o]);
  }
  __syncthreads();
  // V store, TILE-MAJOR: Vt[bz][tile][ch][kin]. thread t -> ch t>>5,
  // keys 2*(t&31), 2*(t&31)+1 (one dword, same tile). Wave = two 128 B
  // segments -> coalesced.
  {
    int ch = tid >> 5, idx = tid & 31;
    unsigned v = ((unsigned*)smV)[ch * 32 + idx];
    int tile = blockIdx.x * 2 + (idx >> 4);      // key64 = 2*idx
    int kin = (2 * idx) & 31;
    *(unsigned*)(Vt + (size_t)bz * C2 * HW4 + (size_t)tile * (C2 * 32) +
                 (size_t)(og * 8 + ch) * 32 + kin) = v;
  }
}

// ---------------------------------------------------------------------------
// Kernel 2: MFMA flash attention — R30: R24 body + FULL NEXT-TILE PREFETCH.
// Rationale: R16/R21 prefetch probes were neutral UNDER THE SCATTERED-V
// REGIME (~280 cyc service time = bandwidth-bound; prefetch can't help).
// Tile-major V (R24) changed the regime: loads contiguous, cheap to serve;
// the residual ~21% idle (VALUBusy 45 + MfmaUtil 34 = 79% combined) is now
// plausibly EXPOSED L2 LATENCY (~250 cyc x 32 iters x 4 waves ~= 13 µs) —
// prefetch has never been tested in this regime. All 4 loads of tile t+1
// issued at top of iter t, pinned with sched_barrier(0); compute reads
// tile t from registers. +32 VGPR (~96 < 128 cap). Tile order 0..31
// unchanged -> bitwise-identical.
// Pre-commit: neutral result -> latency hypothesis dead -> ROOFLINE next.
// ---------------------------------------------------------------------------
__global__ __launch_bounds__(256, 4) void attn_mfma_kern(
    const unsigned short* __restrict__ Qb, const unsigned short* __restrict__ Kb,
    const unsigned short* __restrict__ Vt, float* __restrict__ Y) {
  __shared__ float smY[3][64][33];   // 25.3 KB
  __shared__ float smL[4][64];       // 1 KB
  int lane = threadIdx.x & 63;
  int wv = threadIdx.x >> 6;
  int quad = lane >> 4, l16 = lane & 15;
  int bz = blockIdx.y;
  int qrow0 = blockIdx.x * 64;

  short8 qf[4];
#pragma unroll
  for (int f = 0; f < 4; ++f)
    qf[f] = *(const short8*)(Qb + ((size_t)bz * HW + qrow0 + f * 16 + l16) * C2 + quad * 8);
  const unsigned short* kb = Kb + ((size_t)bz * HW4 + wv * 1024) * C2;
  // wave wv's quarter = tiles wv*32 .. wv*32+31; one tile = C2*32 = 1024 shorts
  const unsigned short* vb = Vt + (size_t)bz * C2 * HW4 + (size_t)(wv * 32) * 1024;

  short8 ones;
#pragma unroll
  for (int i = 0; i < 8; ++i) ones[i] = (short)0x3F80;  // bf16 1.0

  float4v z = {0.f, 0.f, 0.f, 0.f};
  float4v ya[4] = {z, z, z, z};   // y cols l16 (ch 0..15)
  float4v yh[4] = {z, z, z, z};   // y cols 16+l16
  float4v y2[4] = {z, z, z, z};   // row sums l (ones-MFMA)
  float4v moff = {-OFFE, -OFFE, -OFFE, -OFFE};

  // prefetch tile 0 (all four loads)
  short8 ka = *(const short8*)(kb + (size_t)l16 * C2 + quad * 8);
  short8 kh = *(const short8*)(kb + (size_t)(16 + l16) * C2 + quad * 8);
  short8 va = *(const short8*)(vb + l16 * 32 + quad * 8);
  short8 vh = *(const short8*)(vb + (16 + l16) * 32 + quad * 8);

  for (int t = 0; t < 32; ++t) {
    // issue ALL FOUR loads of tile t+1 now; they fly over this iter's compute
    int tn = (t + 1) & 31;                       // t=31 wraps: harmless reload
    const unsigned short* ktn = kb + (size_t)tn * 32 * C2;
    const unsigned short* vtn = vb + (size_t)tn * 1024;
    short8 nka = *(const short8*)(ktn + (size_t)l16 * C2 + quad * 8);
    short8 nkh = *(const short8*)(ktn + (size_t)(16 + l16) * C2 + quad * 8);
    short8 nva = *(const short8*)(vtn + l16 * 32 + quad * 8);
    short8 nvh = *(const short8*)(vtn + (16 + l16) * 32 + quad * 8);
    __builtin_amdgcn_sched_barrier(0);           // pin load issue HERE

    // depth-first per-fragment body — EXACT R24 form (proven best schedule)
#pragma unroll
    for (int f = 0; f < 4; ++f) {
      float4v sa = __builtin_amdgcn_mfma_f32_16x16x32_bf16(ka, qf[f], moff, 0, 0, 0);
      float4v sh = __builtin_amdgcn_mfma_f32_16x16x32_bf16(kh, qf[f], moff, 0, 0, 0);
      float e0 = __builtin_amdgcn_exp2f(sa[0]), e1 = __builtin_amdgcn_exp2f(sa[1]);
      float e2 = __builtin_amdgcn_exp2f(sa[2]), e3 = __builtin_amdgcn_exp2f(sa[3]);
      float g0 = __builtin_amdgcn_exp2f(sh[0]), g1 = __builtin_amdgcn_exp2f(sh[1]);
      float g2 = __builtin_amdgcn_exp2f(sh[2]), g3 = __builtin_amdgcn_exp2f(sh[3]);
      uint4v d = {packtrunc(e0, e1), packtrunc(e2, e3),
                  packtrunc(g0, g1), packtrunc(g2, g3)};
      short8 pf = __builtin_bit_cast(short8, d);
      ya[f] = __builtin_amdgcn_mfma_f32_16x16x32_bf16(pf, va,   ya[f], 0, 0, 0);
      yh[f] = __builtin_amdgcn_mfma_f32_16x16x32_bf16(pf, vh,   yh[f], 0, 0, 0);
      y2[f] = __builtin_amdgcn_mfma_f32_16x16x32_bf16(pf, ones, y2[f], 0, 0, 0);
    }

    ka = nka; kh = nkh; va = nva; vh = nvh;
  }

  // merge the 4 key quarters (R0 epilogue, unchanged)
  if (l16 == 0) {
#pragma unroll
    for (int f = 0; f < 4; ++f)
#pragma unroll
      for (int r = 0; r < 4; ++r)
        smL[wv][f * 16 + quad * 4 + r] = y2[f][r];   // cols identical
  }
  if (wv > 0) {
    int pi = wv - 1;
#pragma unroll
    for (int f = 0; f < 4; ++f)
#pragma unroll
      for (int r = 0; r < 4; ++r) {
        int lr = f * 16 + quad * 4 + r;
        smY[pi][lr][l16] = ya[f][r];
        smY[pi][lr][16 + l16] = yh[f][r];
      }
  }
  __syncthreads();
  if (wv == 0) {
#pragma unroll
    for (int f = 0; f < 4; ++f)
#pragma unroll
      for (int r = 0; r < 4; ++r) {
        int lr = f * 16 + quad * 4 + r;
        float a0 = ya[f][r] + smY[0][lr][l16] + smY[1][lr][l16] + smY[2][lr][l16];
        float a1 = yh[f][r] + smY[0][lr][16 + l16] + smY[1][lr][16 + l16] + smY[2][lr][16 + l16];
        float L = smL[0][lr] + smL[1][lr] + smL[2][lr] + smL[3][lr];
        float inv = 1.f / L;
        size_t rw = (size_t)bz * HW + qrow0 + lr;
        Y[rw * C2 + l16] = a0 * inv;
        Y[rw * C2 + 16 + l16] = a1 * inv;
      }
  }
}

// ---------------------------------------------------------------------------
// Kernel 3: output conv (32->64) + bias + residual — EXACT R4 version
// (best measured; R21 LDS staging regressed). cog split x8, 2048 blocks.
// ---------------------------------------------------------------------------
__global__ __launch_bounds__(256) void conv_out_kern(
    const float* __restrict__ Y, const float* __restrict__ x,
    const float* __restrict__ w, const float* __restrict__ bias,
    float* __restrict__ out) {
  int p = blockIdx.x * 256 + threadIdx.x;
  int cog = blockIdx.y, bz = blockIdx.z;    // cog 0..7 -> channels cog*8..+7
  const float* xb = x + (size_t)bz * Cin * HW + p;
  float xr[8];
#pragma unroll
  for (int i = 0; i < 8; ++i)               // residual loads in flight
    xr[i] = xb[(size_t)(cog * 8 + i) * HW];
  float y[C2];
  const float4* yp4 = (const float4*)(Y + ((size_t)bz * HW + p) * C2);
#pragma unroll
  for (int i = 0; i < 8; ++i) {
    float4 t = yp4[i];
    y[4 * i] = t.x; y[4 * i + 1] = t.y; y[4 * i + 2] = t.z; y[4 * i + 3] = t.w;
  }
  float* ob = out + (size_t)bz * Cin * HW + p;
#pragma unroll
  for (int i = 0; i < 8; ++i) {
    int co = cog * 8 + i;
    float s = bias[co];
#pragma unroll
    for (int o = 0; o < C2; ++o) s = fmaf(w[co * C2 + o], y[o], s);  // s_load
    ob[(size_t)co * HW] = s + xr[i];
  }
}

// ---------------------------------------------------------------------------
extern "C" void kernel_launch(void* const* d_in, const int* in_sizes, int n_in,
                              void* d_out, int out_size, void* d_ws, size_t ws_size,
                              hipStream_t stream) {
  const float* x       = (const float*)d_in[0];
  const float* w_theta = (const float*)d_in[1];
  const float* b_theta = (const float*)d_in[2];
  const float* w_phi   = (const float*)d_in[3];
  const float* b_phi   = (const float*)d_in[4];
  const float* w_g     = (const float*)d_in[5];
  const float* b_g     = (const float*)d_in[6];
  const float* w_out   = (const float*)d_in[7];
  const float* b_out   = (const float*)d_in[8];
  float* out = (float*)d_out;

  float* Yws = (float*)d_ws;                                   // 8 MB fp32
  unsigned short* Qb = (unsigned short*)(Yws + (size_t)4 * HW * C2);
  unsigned short* Kb = Qb + (size_t)4 * HW * C2;
  unsigned short* Vt = Kb + (size_t)4 * HW4 * C2;

  conv_qkv_kern<<<dim3(64, 4, 4), 256, 0, stream>>>(
      x, w_theta, b_theta, w_phi, b_phi, w_g, b_g, Qb, Kb, Vt);
  attn_mfma_kern<<<dim3(HW / 64, 4), 256, 0, stream>>>(Qb, Kb, Vt, Yws);
  conv_out_kern<<<dim3(64, 8, 4), 256, 0, stream>>>(Yws, x, w_out, b_out, out);
}

// Round 17
// 152.046 us; speedup vs baseline: 1.0096x; 1.0096x over previous
//
#include <hip/hip_runtime.h>

#define HW    16384   // 128*128
#define Wh    128
#define Cin   64
#define C2    32
#define HW4   4096    // 64*64

typedef short short8 __attribute__((ext_vector_type(8)));     // 8 bf16 = 4 VGPRs
typedef float float4v __attribute__((ext_vector_type(4)));
typedef unsigned uint4v __attribute__((ext_vector_type(4)));

#define LOG2E 1.44269504f
#define OFFE  43.2808512f   // 30*log2(e): exp(s-30) == exp2(s*log2e - OFFE)

__device__ __forceinline__ unsigned pack2bf16(float lo, float hi) {
  unsigned ul = __builtin_bit_cast(unsigned, lo);
  unsigned uh = __builtin_bit_cast(unsigned, hi);
  ul = (ul + 0x7fffu + ((ul >> 16) & 1u)) >> 16;
  uh = (uh + 0x7fffu + ((uh >> 16) & 1u)) & 0xffff0000u;
  return ul | uh;
}
__device__ __forceinline__ unsigned short f2bf(float f) {
  unsigned u = __builtin_bit_cast(unsigned, f);
  return (unsigned short)((u + 0x7fffu + ((u >> 16) & 1u)) >> 16);
}
// RTZ-truncate two fp32 to bf16, lo in [15:0], hi in [31:16]
__device__ __forceinline__ unsigned packtrunc(float lo, float hi) {
  return __builtin_amdgcn_perm(__builtin_bit_cast(unsigned, hi),
                               __builtin_bit_cast(unsigned, lo), 0x07060302u);
}

// ---------------------------------------------------------------------------
// Kernel 1: FUSED theta+phi+g conv (+2x2 maxpool) — R29 form: repack folded
// in bitwise-identically (wt*LOG2E v_mul == repack's stored value; fmaf
// chain unchanged), tile-major V store (R24 layout).
// Probe history: async global_load_lds staging neutral (R18); barrier-free
// rewrite -12 µs (R19); occupancy-doubling og-split neutral (R28) -> at
// issue floor.
// ---------------------------------------------------------------------------
__global__ __launch_bounds__(256) void conv_qkv_kern(
    const float* __restrict__ x,
    const float* __restrict__ wt, const float* __restrict__ bt,
    const float* __restrict__ wp, const float* __restrict__ bp,
    const float* __restrict__ wg, const float* __restrict__ bg,
    unsigned short* __restrict__ Q, unsigned short* __restrict__ K,
    unsigned short* __restrict__ Vt) {
  __shared__ float smX[2][8][256];               // 16 KB, double-buffered
  __shared__ unsigned short smV[8][64];          // 1 KB
  int tid = threadIdx.x;
  int og = blockIdx.y, bz = blockIdx.z;
  int pxbase = blockIdx.x * 2 * Wh;              // full-res rows 2i, 2i+1
  int jloc = tid >> 2;                           // pooled col 0..63
  int rpar = (tid >> 1) & 1, cpar = tid & 1;
  int myPx = rpar * Wh + 2 * jloc + cpar;        // local pixel 0..255
  const float* xb = x + (size_t)bz * Cin * HW + pxbase;
  const float* wts = wt + (size_t)og * 8 * Cin;  // uniform -> s_load
  const float* wps = wp + (size_t)og * 8 * Cin;
  const float* wgs = wg + (size_t)og * 8 * Cin;

  // stage chunk: 512 float4 = 256 threads x 2; ch = f>>6, p4 = f&63
  auto stage = [&](int cb8, int buf) {
#pragma unroll
    for (int u = 0; u < 2; ++u) {
      int f = u * 256 + tid;
      int ch = f >> 6, p4 = f & 63;
      *(float4*)&smX[buf][ch][p4 * 4] =
          *(const float4*)(xb + (size_t)(cb8 * 8 + ch) * HW + p4 * 4);
    }
  };

  // acc[0..7]=theta (pre-scaled by LOG2E), acc[8..15]=phi, acc[16..23]=g
  float acc[24];
#pragma unroll
  for (int k = 0; k < 8; ++k) {
    acc[k] = bt[og * 8 + k] * LOG2E;             // == repack's bAll value
    acc[8 + k] = bp[og * 8 + k];
    acc[16 + k] = bg[og * 8 + k];
  }

  stage(0, 0);
  __syncthreads();
  for (int cb8 = 0; cb8 < 8; ++cb8) {
    if (cb8 < 7) stage(cb8 + 1, (cb8 + 1) & 1);  // loads fly over compute
    float xv[8];
#pragma unroll
    for (int u = 0; u < 8; ++u) xv[u] = smX[cb8 & 1][u][myPx];
#pragma unroll
    for (int u = 0; u < 8; ++u) {
      int ch = cb8 * 8 + u;
#pragma unroll
      for (int k = 0; k < 8; ++k) {
        acc[k]      = fmaf(wts[k * Cin + ch] * LOG2E, xv[u], acc[k]);
        acc[8 + k]  = fmaf(wps[k * Cin + ch], xv[u], acc[8 + k]);
        acc[16 + k] = fmaf(wgs[k * Cin + ch], xv[u], acc[16 + k]);
      }
    }
    __syncthreads();                             // staged buf ready for next
  }

  int pp = blockIdx.x * 64 + jloc;               // global pooled pixel
  int p = pxbase + myPx;                         // global full-res pixel
  // theta -> Q
  {
    uint4 up;
    up.x = pack2bf16(acc[0], acc[1]); up.y = pack2bf16(acc[2], acc[3]);
    up.z = pack2bf16(acc[4], acc[5]); up.w = pack2bf16(acc[6], acc[7]);
    *(uint4*)(Q + ((size_t)bz * HW + p) * C2 + og * 8) = up;
  }
  // 2x2 maxpool across lane-mates {4j..4j+3}
  float aP[8], aG[8];
#pragma unroll
  for (int o = 0; o < 8; ++o) {
    float vp = acc[8 + o], vg = acc[16 + o];
    vp = fmaxf(vp, __shfl_xor(vp, 1)); vp = fmaxf(vp, __shfl_xor(vp, 2));
    vg = fmaxf(vg, __shfl_xor(vg, 1)); vg = fmaxf(vg, __shfl_xor(vg, 2));
    aP[o] = vp; aG[o] = vg;
  }
  if ((tid & 3) == 0) {
    int loc = pp & 31, tile = pp >> 5;
    int prow = ((loc & 4) << 2) + ((loc >> 3) << 2) + (loc & 3);   // S^T perm
    uint4 up;
    up.x = pack2bf16(aP[0], aP[1]); up.y = pack2bf16(aP[2], aP[3]);
    up.z = pack2bf16(aP[4], aP[5]); up.w = pack2bf16(aP[6], aP[7]);
    *(uint4*)(K + ((size_t)bz * HW4 + tile * 32 + prow) * C2 + og * 8) = up;
#pragma unroll
    for (int o = 0; o < 8; ++o) smV[o][tid >> 2] = f2bf(aG[o]);
  }
  __syncthreads();
  // V store, TILE-MAJOR: Vt[bz][tile][ch][kin]. thread t -> ch t>>5,
  // keys 2*(t&31), 2*(t&31)+1 (one dword, same tile). Wave = two 128 B
  // segments -> coalesced.
  {
    int ch = tid >> 5, idx = tid & 31;
    unsigned v = ((unsigned*)smV)[ch * 32 + idx];
    int tile = blockIdx.x * 2 + (idx >> 4);      // key64 = 2*idx
    int kin = (2 * idx) & 31;
    *(unsigned*)(Vt + (size_t)bz * C2 * HW4 + (size_t)tile * (C2 * 32) +
                 (size_t)(og * 8 + ch) * 32 + kin) = v;
  }
}

// ---------------------------------------------------------------------------
// Kernel 2: MFMA flash attention — EXACT R24 form, the best-measured attn
// (48.2-48.7 µs). Session verdict: dependency-chain-bound; MfmaUtil+
// VALUBusy ~80% combined. Probes closed: scheduling x6 (fences/pins/
// setprio/breadth-first: neutral or worse), occupancy x3 (2/4/6/8 waves:
// flat), load count x3 (halve neutral, double 1.6x worse), prefetch in
// contiguous regime (R30: -1.4 µs), 2-tile unroll (neutral). The one real
// lever was load SHAPE: tile-major V, +11 µs (R24). Floor arithmetic:
// max(MFMA ~45k, VALU+trans ~54k cyc/SIMD) ~= 23 µs; the remaining gap is
// MFMA<->VALU serialization that source-level HIP cannot re-schedule
// (hand-asm interleave territory).
// ---------------------------------------------------------------------------
__global__ __launch_bounds__(256, 4) void attn_mfma_kern(
    const unsigned short* __restrict__ Qb, const unsigned short* __restrict__ Kb,
    const unsigned short* __restrict__ Vt, float* __restrict__ Y) {
  __shared__ float smY[3][64][33];   // 25.3 KB
  __shared__ float smL[4][64];       // 1 KB
  int lane = threadIdx.x & 63;
  int wv = threadIdx.x >> 6;
  int quad = lane >> 4, l16 = lane & 15;
  int bz = blockIdx.y;
  int qrow0 = blockIdx.x * 64;

  short8 qf[4];
#pragma unroll
  for (int f = 0; f < 4; ++f)
    qf[f] = *(const short8*)(Qb + ((size_t)bz * HW + qrow0 + f * 16 + l16) * C2 + quad * 8);
  const unsigned short* kb = Kb + ((size_t)bz * HW4 + wv * 1024) * C2;
  // wave wv's quarter = tiles wv*32 .. wv*32+31; one tile = C2*32 = 1024 shorts
  const unsigned short* vb = Vt + (size_t)bz * C2 * HW4 + (size_t)(wv * 32) * 1024;

  short8 ones;
#pragma unroll
  for (int i = 0; i < 8; ++i) ones[i] = (short)0x3F80;  // bf16 1.0

  float4v z = {0.f, 0.f, 0.f, 0.f};
  float4v ya[4] = {z, z, z, z};   // y cols l16 (ch 0..15)
  float4v yh[4] = {z, z, z, z};   // y cols 16+l16
  float4v y2[4] = {z, z, z, z};   // row sums l (ones-MFMA)
  float4v moff = {-OFFE, -OFFE, -OFFE, -OFFE};

  for (int t = 0; t < 32; ++t) {
    const unsigned short* kt = kb + (size_t)t * 32 * C2;
    const unsigned short* vt = vb + (size_t)t * 1024;
    short8 ka = *(const short8*)(kt + (size_t)l16 * C2 + quad * 8);
    short8 kh = *(const short8*)(kt + (size_t)(16 + l16) * C2 + quad * 8);
    short8 va = *(const short8*)(vt + l16 * 32 + quad * 8);          // 1 KB contig
    short8 vh = *(const short8*)(vt + (16 + l16) * 32 + quad * 8);   // next 1 KB
#pragma unroll
    for (int f = 0; f < 4; ++f) {
      float4v sa = __builtin_amdgcn_mfma_f32_16x16x32_bf16(ka, qf[f], moff, 0, 0, 0);
      float4v sh = __builtin_amdgcn_mfma_f32_16x16x32_bf16(kh, qf[f], moff, 0, 0, 0);
      float e0 = __builtin_amdgcn_exp2f(sa[0]), e1 = __builtin_amdgcn_exp2f(sa[1]);
      float e2 = __builtin_amdgcn_exp2f(sa[2]), e3 = __builtin_amdgcn_exp2f(sa[3]);
      float g0 = __builtin_amdgcn_exp2f(sh[0]), g1 = __builtin_amdgcn_exp2f(sh[1]);
      float g2 = __builtin_amdgcn_exp2f(sh[2]), g3 = __builtin_amdgcn_exp2f(sh[3]);
      uint4v d = {packtrunc(e0, e1), packtrunc(e2, e3),
                  packtrunc(g0, g1), packtrunc(g2, g3)};
      short8 pf = __builtin_bit_cast(short8, d);
      ya[f] = __builtin_amdgcn_mfma_f32_16x16x32_bf16(pf, va,   ya[f], 0, 0, 0);
      yh[f] = __builtin_amdgcn_mfma_f32_16x16x32_bf16(pf, vh,   yh[f], 0, 0, 0);
      y2[f] = __builtin_amdgcn_mfma_f32_16x16x32_bf16(pf, ones, y2[f], 0, 0, 0);
    }
  }

  // merge the 4 key quarters (R0 epilogue, unchanged)
  if (l16 == 0) {
#pragma unroll
    for (int f = 0; f < 4; ++f)
#pragma unroll
      for (int r = 0; r < 4; ++r)
        smL[wv][f * 16 + quad * 4 + r] = y2[f][r];   // cols identical
  }
  if (wv > 0) {
    int pi = wv - 1;
#pragma unroll
    for (int f = 0; f < 4; ++f)
#pragma unroll
      for (int r = 0; r < 4; ++r) {
        int lr = f * 16 + quad * 4 + r;
        smY[pi][lr][l16] = ya[f][r];
        smY[pi][lr][16 + l16] = yh[f][r];
      }
  }
  __syncthreads();
  if (wv == 0) {
#pragma unroll
    for (int f = 0; f < 4; ++f)
#pragma unroll
      for (int r = 0; r < 4; ++r) {
        int lr = f * 16 + quad * 4 + r;
        float a0 = ya[f][r] + smY[0][lr][l16] + smY[1][lr][l16] + smY[2][lr][l16];
        float a1 = yh[f][r] + smY[0][lr][16 + l16] + smY[1][lr][16 + l16] + smY[2][lr][16 + l16];
        float L = smL[0][lr] + smL[1][lr] + smL[2][lr] + smL[3][lr];
        float inv = 1.f / L;
        size_t rw = (size_t)bz * HW + qrow0 + lr;
        Y[rw * C2 + l16] = a0 * inv;
        Y[rw * C2 + 16 + l16] = a1 * inv;
      }
  }
}

// ---------------------------------------------------------------------------
// Kernel 3: output conv (32->64) + bias + residual — EXACT R4 version
// (best measured; R21 LDS staging regressed). cog split x8, 2048 blocks.
// ---------------------------------------------------------------------------
__global__ __launch_bounds__(256) void conv_out_kern(
    const float* __restrict__ Y, const float* __restrict__ x,
    const float* __restrict__ w, const float* __restrict__ bias,
    float* __restrict__ out) {
  int p = blockIdx.x * 256 + threadIdx.x;
  int cog = blockIdx.y, bz = blockIdx.z;    // cog 0..7 -> channels cog*8..+7
  const float* xb = x + (size_t)bz * Cin * HW + p;
  float xr[8];
#pragma unroll
  for (int i = 0; i < 8; ++i)               // residual loads in flight
    xr[i] = xb[(size_t)(cog * 8 + i) * HW];
  float y[C2];
  const float4* yp4 = (const float4*)(Y + ((size_t)bz * HW + p) * C2);
#pragma unroll
  for (int i = 0; i < 8; ++i) {
    float4 t = yp4[i];
    y[4 * i] = t.x; y[4 * i + 1] = t.y; y[4 * i + 2] = t.z; y[4 * i + 3] = t.w;
  }
  float* ob = out + (size_t)bz * Cin * HW + p;
#pragma unroll
  for (int i = 0; i < 8; ++i) {
    int co = cog * 8 + i;
    float s = bias[co];
#pragma unroll
    for (int o = 0; o < C2; ++o) s = fmaf(w[co * C2 + o], y[o], s);  // s_load
    ob[(size_t)co * HW] = s + xr[i];
  }
}

// ---------------------------------------------------------------------------
extern "C" void kernel_launch(void* const* d_in, const int* in_sizes, int n_in,
                              void* d_out, int out_size, void* d_ws, size_t ws_size,
                              hipStream_t stream) {
  const float* x       = (const float*)d_in[0];
  const float* w_theta = (const float*)d_in[1];
  const float* b_theta = (const float*)d_in[2];
  const float* w_phi   = (const float*)d_in[3];
  const float* b_phi   = (const float*)d_in[4];
  const float* w_g     = (const float*)d_in[5];
  const float* b_g     = (const float*)d_in[6];
  const float* w_out   = (const float*)d_in[7];
  const float* b_out   = (const float*)d_in[8];
  float* out = (float*)d_out;

  float* Yws = (float*)d_ws;                                   // 8 MB fp32
  unsigned short* Qb = (unsigned short*)(Yws + (size_t)4 * HW * C2);
  unsigned short* Kb = Qb + (size_t)4 * HW * C2;
  unsigned short* Vt = Kb + (size_t)4 * HW4 * C2;

  conv_qkv_kern<<<dim3(64, 4, 4), 256, 0, stream>>>(
      x, w_theta, b_theta, w_phi, b_phi, w_g, b_g, Qb, Kb, Vt);
  attn_mfma_kern<<<dim3(HW / 64, 4), 256, 0, stream>>>(Qb, Kb, Vt, Yws);
  conv_out_kern<<<dim3(64, 8, 4), 256, 0, stream>>>(Yws, x, w_out, b_out, out);
}